// Round 2
// baseline (110.707 us; speedup 1.0000x reference)
//
#include <hip/hip_runtime.h>
#include <math.h>

// Chamfer loss, B=16, N=M=4096, D=3, fp32.
// result = sum over all 2*B*N nearest-neighbor sqrt-distances / (2*B*N)
//
// R2 structure (2 kernel nodes, no memset node):
//  kernel 1 (chamfer_main): 512 blocks = (dir, batch, n-chunk, m-split).
//    Stages m-segment (512 pts) in LDS pre-scaled (-2x,-2y,-2z,|t|^2).
//    KPT=8 n-points/thread in regs; inner loop 4 m-points/iter via 4x
//    broadcast ds_read_b128; 12 fma + 2 v_min3 per 4 pairs (3.5 VALU/pair).
//    Writes partial mins COALESCED as partial[split][g] (R1 had 8x write
//    amplification from [g][split] layout: WRITE_SIZE 32MB vs 4MB ideal).
//    Block 0 also zeroes acc+counter (visible to kernel 2 via stream order).
//  kernel 2 (chamfer_combine): min over 8 splits, + |p|^2, clamp, sqrt,
//    block-reduce, atomicAdd to acc; ticket counter -> last block writes out.
//    (R1 had a separate 1-block final kernel; per-node overhead ~15us each.)

#define BATCH   16
#define NPTS    4096
#define THREADS 256
#define KPT     8
#define NCHUNKS 2          // NPTS / (THREADS*KPT)
#define SPLITS  8
#define MSEG    (NPTS / SPLITS)          // 512
#define NITEMS  (2 * BATCH * NPTS)       // 131072
#define CBLOCKS (NITEMS / THREADS)       // 512

__global__ __launch_bounds__(THREADS) void chamfer_main(
    const float* __restrict__ pred, const float* __restrict__ target,
    float* __restrict__ partial, float* __restrict__ acc, int* __restrict__ counter)
{
    __shared__ __align__(16) float xs[MSEG];
    __shared__ __align__(16) float ys[MSEG];
    __shared__ __align__(16) float zs[MSEG];
    __shared__ __align__(16) float ts[MSEG];

    // Zero the accumulator + ticket for kernel 2 (stream order guarantees
    // visibility: all of chamfer_main completes before chamfer_combine starts).
    if (blockIdx.x == 0 && threadIdx.x == 0) {
        acc[0] = 0.0f;
        counter[0] = 0;
    }

    int id = blockIdx.x;
    int split = id & (SPLITS - 1);  id >>= 3;
    int chunk = id & (NCHUNKS - 1); id >>= 1;
    int b     = id & (BATCH - 1);   id >>= 4;
    int dir   = id;                 // 0: pred->target, 1: target->pred

    const float* src = dir ? target : pred;   // n-side (query points)
    const float* dst = dir ? pred : target;   // m-side (candidate points)

    const float* dbase = dst + (size_t)b * (NPTS * 3) + (size_t)split * (MSEG * 3);
    int tid = threadIdx.x;

    // Stage m-segment, pre-scaled.
    for (int i = tid; i < MSEG; i += THREADS) {
        float x = dbase[i * 3 + 0];
        float y = dbase[i * 3 + 1];
        float z = dbase[i * 3 + 2];
        xs[i] = -2.0f * x;
        ys[i] = -2.0f * y;
        zs[i] = -2.0f * z;
        ts[i] = x * x + y * y + z * z;
    }
    __syncthreads();

    // Load KPT query points into registers.
    const float* sbase = src + (size_t)b * (NPTS * 3) + (size_t)chunk * (THREADS * KPT * 3);
    float px[KPT], py[KPT], pz[KPT], mn[KPT];
#pragma unroll
    for (int k = 0; k < KPT; ++k) {
        int n = k * THREADS + tid;
        px[k] = sbase[n * 3 + 0];
        py[k] = sbase[n * 3 + 1];
        pz[k] = sbase[n * 3 + 2];
        mn[k] = 1e30f;
    }

    const float4* x4 = (const float4*)xs;
    const float4* y4 = (const float4*)ys;
    const float4* z4 = (const float4*)zs;
    const float4* t4 = (const float4*)ts;

#pragma unroll 2
    for (int mm = 0; mm < MSEG / 4; ++mm) {
        float4 xv = x4[mm];
        float4 yv = y4[mm];
        float4 zv = z4[mm];
        float4 tv = t4[mm];
#pragma unroll
        for (int k = 0; k < KPT; ++k) {
            float d0 = fmaf(px[k], xv.x, fmaf(py[k], yv.x, fmaf(pz[k], zv.x, tv.x)));
            float d1 = fmaf(px[k], xv.y, fmaf(py[k], yv.y, fmaf(pz[k], zv.y, tv.y)));
            float d2 = fmaf(px[k], xv.z, fmaf(py[k], yv.z, fmaf(pz[k], zv.z, tv.z)));
            float d3 = fmaf(px[k], xv.w, fmaf(py[k], yv.w, fmaf(pz[k], zv.w, tv.w)));
            // Two chained 3-way mins -> v_min3_f32 x2 (vs 4x v_min_f32).
            float m012 = fminf(fminf(d0, d1), d2);
            mn[k] = fminf(fminf(m012, d3), mn[k]);
        }
    }

    // Coalesced partial layout: partial[split * NITEMS + g], g = (dir*B+b)*NPTS + n.
    size_t gbase = (size_t)split * NITEMS + ((size_t)dir * BATCH + b) * NPTS;
#pragma unroll
    for (int k = 0; k < KPT; ++k) {
        int n = chunk * (THREADS * KPT) + k * THREADS + tid;
        partial[gbase + n] = mn[k];
    }
}

__global__ __launch_bounds__(THREADS) void chamfer_combine(
    const float* __restrict__ pred, const float* __restrict__ target,
    const float* __restrict__ partial, float* __restrict__ acc,
    int* __restrict__ counter, float* __restrict__ out)
{
    __shared__ float red[4];
    int g = blockIdx.x * THREADS + threadIdx.x;   // 0..131071
    int dir = g >> 16;                            // 0..1
    int bn  = g & 65535;                          // b*NPTS + n

    const float* src = dir ? target : pred;
    float x = src[bn * 3 + 0];
    float y = src[bn * 3 + 1];
    float z = src[bn * 3 + 2];
    float pp = x * x + y * y + z * z;

    float m = partial[g];
#pragma unroll
    for (int s = 1; s < SPLITS; ++s)
        m = fminf(m, partial[(size_t)s * NITEMS + g]);

    float d = sqrtf(fmaxf(m + pp, 0.0f));

    // Block reduction.
    float v = d;
#pragma unroll
    for (int off = 32; off > 0; off >>= 1)
        v += __shfl_down(v, off);
    int lane = threadIdx.x & 63;
    int wave = threadIdx.x >> 6;
    if (lane == 0) red[wave] = v;
    __syncthreads();

    if (threadIdx.x == 0) {
        float s = red[0] + red[1] + red[2] + red[3];
        atomicAdd(acc, s);                 // device-scope by default on gfx950
        __threadfence();                   // make acc-add visible before ticket
        int old = atomicAdd(counter, 1);
        if (old == CBLOCKS - 1) {
            // All 512 acc-adds are ordered before their counter-adds; reading
            // acc atomically returns the complete sum.
            float tot = atomicAdd(acc, 0.0f);
            out[0] = tot * (1.0f / (float)NITEMS);
        }
    }
}

extern "C" void kernel_launch(void* const* d_in, const int* in_sizes, int n_in,
                              void* d_out, int out_size, void* d_ws, size_t ws_size,
                              hipStream_t stream) {
    const float* pred   = (const float*)d_in[0];
    const float* target = (const float*)d_in[1];
    float* out = (float*)d_out;

    float* partial = (float*)d_ws;                        // NITEMS*SPLITS floats = 4 MB
    float* acc     = partial + (size_t)NITEMS * SPLITS;   // 1 float
    int*   counter = (int*)(acc + 1);                     // 1 int

    chamfer_main<<<2 * BATCH * NCHUNKS * SPLITS, THREADS, 0, stream>>>(
        pred, target, partial, acc, counter);
    chamfer_combine<<<CBLOCKS, THREADS, 0, stream>>>(
        pred, target, partial, acc, counter, out);
}

// Round 3
// 86.492 us; speedup vs baseline: 1.2800x; 1.2800x over previous
//
#include <hip/hip_runtime.h>
#include <math.h>
#include <stdint.h>

// Chamfer loss, B=16, N=M=4096, D=3, fp32 in/out — MFMA formulation.
//
// d^2(p,t) = |p|^2 + (|t|^2 - 2 p.t). The parenthesized term is computed for
// 32x32 tiles by v_mfma_f32_32x32x16_f16 with K-slot packing:
//   A row (candidate t): [tx, ty, tz, h1, h2, 0,0,0] (k=0..7; k=8..15 garbage)
//   B col (query p):     [-2px,-2py,-2pz, 1, 1, 0,0,0] (k=0..7; k=8..15 ZERO)
// where h1 = f16(|t|^2), h2 = f16(|t|^2 - h1) recovers |t|^2 to ~1e-6.
// B's zeroed k=8..15 slots annihilate whatever A's hi-lane regs contain, so
// the m-tile loop needs no masking and no LDS zero region.
// All f16 products are exact in the fp32 MFMA accumulator; the only error is
// f16 quantization of the points themselves (~7e-4/distance, mean ~1e-5).
//
// kernels:
//  1. chamfer_prep: fp32 -> packed 16B/point fragments for both arrays (2 MB ws).
//  2. chamfer_main: 1024 blocks = (dir, b, 128-query group). 4 waves/block,
//     32 query cols/wave held as a constant B-fragment in regs. Loops 64
//     iterations of 2 m-tiles: candidate pack staged LDS via per-wave
//     global_load_lds (redundant across waves -> no __syncthreads in loop;
//     each wave self-syncs with s_waitcnt vmcnt(1) for SW pipelining).
//     Epilogue: 16-reg min tree + shfl_xor(32) -> per-query min, +|p|^2,
//     sqrt, wave/block sum -> blocksum (deterministic, no atomics).
//  3. chamfer_finish: sum 1024 block sums, scale, write out.

#define BATCH   16
#define NPTS    4096
#define THREADS 256
#define NITEMS  (2 * BATCH * NPTS)             // 131072
#define MAIN_BLOCKS (2 * BATCH * (NPTS / 128)) // 1024

typedef __attribute__((ext_vector_type(8)))  _Float16 half8;
typedef __attribute__((ext_vector_type(16))) float    floatx16;

union Pack16 { float4 f4; _Float16 h[8]; half8 h8; };

#define AS1 __attribute__((address_space(1)))
#define AS3 __attribute__((address_space(3)))

__global__ __launch_bounds__(THREADS) void chamfer_prep(
    const float* __restrict__ pred, const float* __restrict__ target,
    float4* __restrict__ packP, float4* __restrict__ packT)
{
    int g = blockIdx.x * THREADS + threadIdx.x;   // 0..131071
    int arr = g >> 16;                            // 0=pred, 1=target
    int pt  = g & 65535;                          // b*NPTS + n
    const float* src = arr ? target : pred;
    float x = src[pt * 3 + 0];
    float y = src[pt * 3 + 1];
    float z = src[pt * 3 + 2];
    _Float16 hx = (_Float16)x, hy = (_Float16)y, hz = (_Float16)z;
    float xf = (float)hx, yf = (float)hy, zf = (float)hz;
    float t = xf * xf + yf * yf + zf * zf;        // |q|^2 of the QUANTIZED point
    _Float16 h1 = (_Float16)t;
    _Float16 h2 = (_Float16)(t - (float)h1);
    Pack16 p;
    p.h[0] = hx; p.h[1] = hy; p.h[2] = hz; p.h[3] = h1; p.h[4] = h2;
    p.h[5] = (_Float16)0.0f; p.h[6] = (_Float16)0.0f; p.h[7] = (_Float16)0.0f;
    (arr ? packT : packP)[pt] = p.f4;
}

__global__ __launch_bounds__(THREADS) void chamfer_main(
    const float4* __restrict__ packP, const float4* __restrict__ packT,
    float* __restrict__ blocksum)
{
    __shared__ float4 abuf[128];   // double buffer: 2 x (64 points x 16B) = 2 KB
    __shared__ float  wsum[4];

    int tid  = threadIdx.x;
    int lane = tid & 63;
    int wave = tid >> 6;
    int l31  = lane & 31;
    bool lo  = lane < 32;

    int id = blockIdx.x;
    int ng = id & 31; id >>= 5;    // query group (128 queries each)
    int b  = id & 15; id >>= 4;
    int dir = id;                  // 0: queries=pred, candidates=target

    const float4* qpack = dir ? packT : packP;
    const float4* cpack = dir ? packP : packT;

    // Per-wave constant B fragment: 32 query cols, col = lane&31.
    // B[k][col]: lanes 0-31 carry k=0..7, lanes 32-63 carry k=8..15 (all zero).
    Pack16 praw;
    praw.f4 = qpack[(size_t)b * NPTS + ng * 128 + wave * 32 + l31];
    float psq = (float)praw.h[3] + (float)praw.h[4];   // |p_q|^2 (fp32-accurate)

    half8 bfrag;
#pragma unroll
    for (int i = 0; i < 8; ++i) bfrag[i] = (_Float16)0.0f;
    if (lo) {
        bfrag[0] = (_Float16)(praw.h[0] * (_Float16)-2.0f);  // exact x2 scale
        bfrag[1] = (_Float16)(praw.h[1] * (_Float16)-2.0f);
        bfrag[2] = (_Float16)(praw.h[2] * (_Float16)-2.0f);
        bfrag[3] = (_Float16)1.0f;
        bfrag[4] = (_Float16)1.0f;
    }

    const float4* cbase = cpack + (size_t)b * NPTS;

    floatx16 zero, mn;
#pragma unroll
    for (int r = 0; r < 16; ++r) { zero[r] = 0.0f; mn[r] = 1e30f; }

    // Prefetch tile-pair 0 (each wave issues its own copy; same bytes, benign).
    __builtin_amdgcn_global_load_lds(
        (const AS1 uint32_t*)(cbase + lane),
        (AS3 uint32_t*)(&abuf[lane]), 16, 0, 0);

#pragma unroll 2
    for (int t = 0; t < 64; ++t) {
        int cur = (t & 1) * 64;
        if (t < 63) {
            __builtin_amdgcn_global_load_lds(
                (const AS1 uint32_t*)(cbase + (t + 1) * 64 + lane),
                (AS3 uint32_t*)(&abuf[((t + 1) & 1) * 64 + lane]), 16, 0, 0);
            __builtin_amdgcn_s_waitcnt(0x0f71);   // vmcnt(1): tile t ready, t+1 in flight
        } else {
            __builtin_amdgcn_s_waitcnt(0x0f70);   // vmcnt(0): last tile
        }
        // A fragments: row = lane&31 (hi lanes read same addr -> broadcast).
        // Hi-lane k=8..15 content is duplicate point data — annihilated by B's zeros.
        Pack16 a0, a1;
        a0.f4 = abuf[cur + l31];
        a1.f4 = abuf[cur + l31 + 32];
        floatx16 d0 = __builtin_amdgcn_mfma_f32_32x32x16_f16(a0.h8, bfrag, zero, 0, 0, 0);
        floatx16 d1 = __builtin_amdgcn_mfma_f32_32x32x16_f16(a1.h8, bfrag, zero, 0, 0, 0);
#pragma unroll
        for (int r = 0; r < 16; ++r)
            mn[r] = fminf(fminf(d0[r], d1[r]), mn[r]);   // v_min3_f32
    }

    // Reduce 16 regs (rows within this half-lane-group) then across lane^32.
    float m0 = fminf(fminf(mn[0], mn[1]),  fminf(mn[2], mn[3]));
    float m1 = fminf(fminf(mn[4], mn[5]),  fminf(mn[6], mn[7]));
    float m2 = fminf(fminf(mn[8], mn[9]),  fminf(mn[10], mn[11]));
    float m3 = fminf(fminf(mn[12], mn[13]), fminf(mn[14], mn[15]));
    float m  = fminf(fminf(m0, m1), fminf(m2, m3));
    m = fminf(m, __shfl_xor(m, 32));      // combine row halves

    float dist = sqrtf(fmaxf(m + psq, 0.0f));

    // Sum over the 32 query cols (lanes 0-31; lanes 32-63 mirror — don't fold ^32).
#pragma unroll
    for (int off = 1; off <= 16; off <<= 1)
        dist += __shfl_xor(dist, off);

    if (lane == 0) wsum[wave] = dist;
    __syncthreads();
    if (tid == 0) blocksum[blockIdx.x] = wsum[0] + wsum[1] + wsum[2] + wsum[3];
}

__global__ __launch_bounds__(THREADS) void chamfer_finish(
    const float4* __restrict__ bs, float* __restrict__ out)
{
    __shared__ float ws[4];
    int tid = threadIdx.x;
    float4 v = bs[tid];                   // 256 threads x 4 = 1024 block sums
    float s = v.x + v.y + v.z + v.w;
#pragma unroll
    for (int off = 1; off <= 32; off <<= 1)
        s += __shfl_xor(s, off);
    int lane = tid & 63, wave = tid >> 6;
    if (lane == 0) ws[wave] = s;
    __syncthreads();
    if (tid == 0) out[0] = (ws[0] + ws[1] + ws[2] + ws[3]) * (1.0f / (float)NITEMS);
}

extern "C" void kernel_launch(void* const* d_in, const int* in_sizes, int n_in,
                              void* d_out, int out_size, void* d_ws, size_t ws_size,
                              hipStream_t stream) {
    const float* pred   = (const float*)d_in[0];
    const float* target = (const float*)d_in[1];
    float* out = (float*)d_out;

    float4* packP = (float4*)d_ws;                        // 1 MB
    float4* packT = packP + (size_t)BATCH * NPTS;         // 1 MB
    float*  blocksum = (float*)(packT + (size_t)BATCH * NPTS);  // 4 KB

    chamfer_prep<<<NITEMS / THREADS, THREADS, 0, stream>>>(pred, target, packP, packT);
    chamfer_main<<<MAIN_BLOCKS, THREADS, 0, stream>>>(packP, packT, blocksum);
    chamfer_finish<<<1, THREADS, 0, stream>>>((const float4*)blocksum, out);
}